// Round 1
// baseline (2597.583 us; speedup 1.0000x reference)
//
#include <hip/hip_runtime.h>

#define NN 100000
#define NE 3200000
#define NG 2048
#define FIN 9
#define HD 64
#define XD 32
#define BN_EPS 1e-5f

__global__ void k_deg_init(float* deg) {
    int i = blockIdx.x * 256 + threadIdx.x;
    if (i < NN) deg[i] = 1.0f;  // self-loop
}

__global__ void k_deg_accum(const int* __restrict__ dst, float* deg) {
    int e = blockIdx.x * 256 + threadIdx.x;
    if (e < NE) atomicAdd(&deg[dst[e]], 1.0f);
}

__global__ void k_rsqrt(float* deg) {
    int i = blockIdx.x * 256 + threadIdx.x;
    if (i < NN) deg[i] = rsqrtf(deg[i]);
}

// out[i][f] = sum_k x[i][k] * W[k][f],  K = FIN
__global__ void k_xform_in(const float* __restrict__ x, const float* __restrict__ W,
                           float* __restrict__ out) {
    __shared__ float Ws[FIN * HD];
    int t = threadIdx.x;
    if (t < FIN * HD) Ws[t] = W[t];
    __syncthreads();
    long gtid = (long)blockIdx.x * 256 + t;
    int i = (int)(gtid >> 6);
    int f = (int)(gtid & 63);
    if (i >= NN) return;
    const float* row = x + (long)i * FIN;
    float acc = 0.f;
#pragma unroll
    for (int k = 0; k < FIN; ++k) acc += row[k] * Ws[k * HD + f];
    out[gtid] = acc;
}

// out[i][f] = sum_k h[i][k] * W[k][f],  K = 64
__global__ void k_xform64(const float* __restrict__ h, const float* __restrict__ W,
                          float* __restrict__ out) {
    __shared__ float Ws[HD * HD];
    int t = threadIdx.x;
    for (int k = t; k < HD * HD; k += 256) Ws[k] = W[k];
    __syncthreads();
    long gtid = (long)blockIdx.x * 256 + t;
    int i = (int)(gtid >> 6);
    int f = (int)(gtid & 63);
    if (i >= NN) return;
    const float* row = h + (long)i * HD;
    float acc = 0.f;
#pragma unroll
    for (int k = 0; k < HD; ++k) acc += row[k] * Ws[k * HD + f];
    out[gtid] = acc;
}

// agg[i][f] = hW[i][f] * dis[i]^2   (self-loop contribution; also zero-inits agg)
__global__ void k_selfinit(const float* __restrict__ hW, const float* __restrict__ dis,
                           float* __restrict__ agg) {
    long gtid = (long)blockIdx.x * 256 + threadIdx.x;
    int i = (int)(gtid >> 6);
    if (i >= NN) return;
    float d = dis[i];
    agg[gtid] = hW[gtid] * d * d;
}

// agg[dst][f] += hW[src][f] * dis[src]*dis[dst]
__global__ void k_edge(const int* __restrict__ src, const int* __restrict__ dst,
                       const float* __restrict__ dis, const float* __restrict__ hW,
                       float* __restrict__ agg) {
    long gtid = (long)blockIdx.x * 256 + threadIdx.x;
    int e = (int)(gtid >> 6);
    int f = (int)(gtid & 63);
    if (e >= NE) return;
    int s = src[e];
    int d = dst[e];
    float c = dis[s] * dis[d];
    atomicAdd(&agg[(long)d * HD + f], hW[(long)s * HD + f] * c);
}

__global__ void k_bias_relu(float* h, const float* __restrict__ b) {
    long gtid = (long)blockIdx.x * 256 + threadIdx.x;
    int i = (int)(gtid >> 6);
    int f = (int)(gtid & 63);
    if (i >= NN) return;
    float v = h[gtid] + b[f];
    h[gtid] = v > 0.f ? v : 0.f;
}

__global__ void k_zero(float* p, long n) {
    long i = (long)blockIdx.x * 256 + threadIdx.x;
    if (i < n) p[i] = 0.f;
}

// z[batch[i]][f] += h[i][f];  cnt[batch[i]] += 1 (f==0)
__global__ void k_pool(const float* __restrict__ h, const int* __restrict__ batch,
                       float* __restrict__ z, float* __restrict__ cnt) {
    long gtid = (long)blockIdx.x * 256 + threadIdx.x;
    int i = (int)(gtid >> 6);
    int f = (int)(gtid & 63);
    if (i >= NN) return;
    int g = batch[i];
    atomicAdd(&z[(long)g * (HD + XD) + f], h[gtid]);
    if (f == 0) atomicAdd(&cnt[g], 1.0f);
}

// z[:, :64] /= max(cnt,1);  z[:, 64:96] = extra
__global__ void k_zfin(float* z, const float* __restrict__ cnt,
                       const float* __restrict__ extra) {
    int gtid = blockIdx.x * 256 + threadIdx.x;
    if (gtid >= NG * (HD + XD)) return;
    int g = gtid / (HD + XD);
    int f = gtid % (HD + XD);
    if (f < HD)
        z[gtid] = z[gtid] / fmaxf(cnt[g], 1.0f);
    else
        z[gtid] = extra[g * XD + (f - HD)];
}

// out[g][m] = b[m] + sum_k in[g][k]*W[k][m]
template <int K, int M>
__global__ void k_mm(const float* __restrict__ in, const float* __restrict__ W,
                     const float* __restrict__ b, float* __restrict__ out) {
    int gtid = blockIdx.x * 256 + threadIdx.x;
    if (gtid >= NG * M) return;
    int g = gtid / M;
    int m = gtid % M;
    const float* row = in + (long)g * K;
    float acc = b[m];
#pragma unroll 8
    for (int k = 0; k < K; ++k) acc += row[k] * W[k * M + m];
    out[gtid] = acc;
}

// column-wise batchnorm (training stats) + relu, in place; one block per column
template <int M>
__global__ void k_bn_relu(float* z, const float* __restrict__ gamma,
                          const float* __restrict__ beta) {
    int c = blockIdx.x;
    int t = threadIdx.x;
    __shared__ float s1[256], s2[256];
    float sum = 0.f, sumsq = 0.f;
    for (int g = t; g < NG; g += 256) {
        float v = z[(long)g * M + c];
        sum += v;
        sumsq += v * v;
    }
    s1[t] = sum;
    s2[t] = sumsq;
    __syncthreads();
    for (int o = 128; o > 0; o >>= 1) {
        if (t < o) {
            s1[t] += s1[t + o];
            s2[t] += s2[t + o];
        }
        __syncthreads();
    }
    float mean = s1[0] / (float)NG;
    float var = s2[0] / (float)NG - mean * mean;
    float scale = rsqrtf(var + BN_EPS) * gamma[c];
    float shift = beta[c] - mean * scale;
    for (int g = t; g < NG; g += 256) {
        float v = z[(long)g * M + c] * scale + shift;
        z[(long)g * M + c] = v > 0.f ? v : 0.f;
    }
}

__global__ void k_final(const float* __restrict__ z2, const float* __restrict__ W,
                        const float* __restrict__ b, float* __restrict__ out) {
    int g = blockIdx.x * 256 + threadIdx.x;
    if (g >= NG) return;
    const float* row = z2 + (long)g * 32;
    float acc = b[0];
#pragma unroll
    for (int k = 0; k < 32; ++k) acc += row[k] * W[k];
    out[g] = acc;
}

extern "C" void kernel_launch(void* const* d_in, const int* in_sizes, int n_in,
                              void* d_out, int out_size, void* d_ws, size_t ws_size,
                              hipStream_t stream) {
    const float* x = (const float*)d_in[0];
    const int* ei = (const int*)d_in[1];   // [2, E] flat: src then dst
    const int* batch = (const int*)d_in[2];
    const float* extra = (const float*)d_in[3];
    const float* W1 = (const float*)d_in[4];
    const float* b1 = (const float*)d_in[5];
    const float* W2 = (const float*)d_in[6];
    const float* b2 = (const float*)d_in[7];
    const float* W3 = (const float*)d_in[8];
    const float* b3 = (const float*)d_in[9];
    const float* Wm0 = (const float*)d_in[10];
    const float* bm0 = (const float*)d_in[11];
    const float* g0 = (const float*)d_in[12];
    const float* be0 = (const float*)d_in[13];
    const float* Wm1 = (const float*)d_in[14];
    const float* bm1 = (const float*)d_in[15];
    const float* g1 = (const float*)d_in[16];
    const float* be1 = (const float*)d_in[17];
    const float* Wm2 = (const float*)d_in[18];
    const float* bm2 = (const float*)d_in[19];
    const float* g2 = (const float*)d_in[20];
    const float* be2 = (const float*)d_in[21];
    const float* Wm3 = (const float*)d_in[22];
    const float* bm3 = (const float*)d_in[23];

    const int* src = ei;
    const int* dst = ei + NE;

    float* ws = (float*)d_ws;
    float* dis = ws;                      // NN (padded to 100352)
    float* A = dis + 100352;              // NN*64
    float* B = A + (long)NN * HD;         // NN*64
    float* z = B + (long)NN * HD;         // NG*96
    float* cnt = z + NG * (HD + XD);      // NG
    float* t0 = cnt + NG;                 // NG*128
    float* t1 = t0 + NG * 128;            // NG*64
    float* t2 = t1 + NG * 64;             // NG*32

    const long NF = (long)NN * HD;        // 6,400,000
    const long EF = (long)NE * HD;        // 204,800,000

    // degree -> dis
    k_deg_init<<<(NN + 255) / 256, 256, 0, stream>>>(dis);
    k_deg_accum<<<(NE + 255) / 256, 256, 0, stream>>>(dst, dis);
    k_rsqrt<<<(NN + 255) / 256, 256, 0, stream>>>(dis);

    dim3 bNF((unsigned)((NF + 255) / 256));
    dim3 bEF((unsigned)((EF + 255) / 256));

    // layer 1
    k_xform_in<<<bNF, 256, 0, stream>>>(x, W1, A);
    k_selfinit<<<bNF, 256, 0, stream>>>(A, dis, B);
    k_edge<<<bEF, 256, 0, stream>>>(src, dst, dis, A, B);
    k_bias_relu<<<bNF, 256, 0, stream>>>(B, b1);
    // layer 2
    k_xform64<<<bNF, 256, 0, stream>>>(B, W2, A);
    k_selfinit<<<bNF, 256, 0, stream>>>(A, dis, B);
    k_edge<<<bEF, 256, 0, stream>>>(src, dst, dis, A, B);
    k_bias_relu<<<bNF, 256, 0, stream>>>(B, b2);
    // layer 3
    k_xform64<<<bNF, 256, 0, stream>>>(B, W3, A);
    k_selfinit<<<bNF, 256, 0, stream>>>(A, dis, B);
    k_edge<<<bEF, 256, 0, stream>>>(src, dst, dis, A, B);
    k_bias_relu<<<bNF, 256, 0, stream>>>(B, b3);

    // pooling
    long zlen = (long)NG * (HD + XD) + NG;
    k_zero<<<(unsigned)((zlen + 255) / 256), 256, 0, stream>>>(z, zlen);
    k_pool<<<bNF, 256, 0, stream>>>(B, batch, z, cnt);
    k_zfin<<<(NG * (HD + XD) + 255) / 256, 256, 0, stream>>>(z, cnt, extra);

    // MLP head
    k_mm<96, 128><<<(NG * 128 + 255) / 256, 256, 0, stream>>>(z, Wm0, bm0, t0);
    k_bn_relu<128><<<128, 256, 0, stream>>>(t0, g0, be0);
    k_mm<128, 64><<<(NG * 64 + 255) / 256, 256, 0, stream>>>(t0, Wm1, bm1, t1);
    k_bn_relu<64><<<64, 256, 0, stream>>>(t1, g1, be1);
    k_mm<64, 32><<<(NG * 32 + 255) / 256, 256, 0, stream>>>(t1, Wm2, bm2, t2);
    k_bn_relu<32><<<32, 256, 0, stream>>>(t2, g2, be2);
    k_final<<<(NG + 255) / 256, 256, 0, stream>>>(t2, Wm3, bm3, (float*)d_out);
}

// Round 2
// 1057.152 us; speedup vs baseline: 2.4572x; 2.4572x over previous
//
#include <hip/hip_runtime.h>

#define NN 100000
#define NE 3200000
#define NG 2048
#define FIN 9
#define HD 64
#define XD 32
#define BN_EPS 1e-5f

// ---------------- CSR build ----------------

__global__ void k_zeroi(int* p, int n) {
    int i = blockIdx.x * 256 + threadIdx.x;
    if (i < n) p[i] = 0;
}

__global__ void k_count(const int* __restrict__ dst, int* __restrict__ cnt) {
    int e = blockIdx.x * 256 + threadIdx.x;
    if (e < NE) atomicAdd(&cnt[dst[e]], 1);
}

__global__ void k_dis(const int* __restrict__ cnt, float* __restrict__ dis) {
    int i = blockIdx.x * 256 + threadIdx.x;
    if (i < NN) dis[i] = rsqrtf((float)cnt[i] + 1.0f);  // +1 self loop
}

// single-block scan: rowptr[0]=0, rowptr[i+1]=sum cnt[0..i]
__global__ __launch_bounds__(1024) void k_scan(const int* __restrict__ cnt,
                                               int* __restrict__ rowptr) {
    __shared__ int wsum[16];
    __shared__ int carry_s;
    int tid = threadIdx.x, lane = tid & 63, wid = tid >> 6;
    if (tid == 0) { carry_s = 0; rowptr[0] = 0; }
    __syncthreads();
    for (int base = 0; base < NN; base += 4096) {
        int i0 = base + tid * 4;
        int v0 = (i0 + 0 < NN) ? cnt[i0 + 0] : 0;
        int v1 = (i0 + 1 < NN) ? cnt[i0 + 1] : 0;
        int v2 = (i0 + 2 < NN) ? cnt[i0 + 2] : 0;
        int v3 = (i0 + 3 < NN) ? cnt[i0 + 3] : 0;
        int s = v0 + v1 + v2 + v3;
        int x = s;
        for (int off = 1; off < 64; off <<= 1) {
            int y = __shfl_up(x, off, 64);
            if (lane >= off) x += y;
        }
        if (lane == 63) wsum[wid] = x;
        __syncthreads();
        if (wid == 0 && lane < 16) {
            int y = wsum[lane];
            for (int off = 1; off < 16; off <<= 1) {
                int z2 = __shfl_up(y, off, 16);
                if (lane >= off) y += z2;
            }
            wsum[lane] = y;
        }
        __syncthreads();
        int wofs = (wid > 0) ? wsum[wid - 1] : 0;
        int total = wsum[15];
        int p = x - s + wofs + carry_s;  // exclusive prefix of this thread's chunk
        if (i0 + 0 < NN) { p += v0; rowptr[i0 + 1] = p; }
        if (i0 + 1 < NN) { p += v1; rowptr[i0 + 2] = p; }
        if (i0 + 2 < NN) { p += v2; rowptr[i0 + 3] = p; }
        if (i0 + 3 < NN) { p += v3; rowptr[i0 + 4] = p; }
        __syncthreads();
        if (tid == 0) carry_s += total;
        __syncthreads();
    }
}

__global__ void k_scatter(const int* __restrict__ src, const int* __restrict__ dst,
                          const int* __restrict__ rowptr, int* __restrict__ cursor,
                          int* __restrict__ srcs) {
    int e = blockIdx.x * 256 + threadIdx.x;
    if (e >= NE) return;
    int d = dst[e];
    int pos = rowptr[d] + atomicAdd(&cursor[d], 1);
    srcs[pos] = src[e];
}

// ---------------- layer 1: aggregate x (padded to 16), then transform ----------------

__global__ void k_padx(const float* __restrict__ x, float* __restrict__ xp) {
    int gtid = blockIdx.x * 256 + threadIdx.x;
    if (gtid >= NN * 16) return;
    int i = gtid >> 4, f = gtid & 15;
    xp[gtid] = (f < FIN) ? x[i * FIN + f] : 0.0f;
}

// 16 lanes per node; aggx[i] = di * ( sum_e dis[s]*xp[s] + di*xp[i] )
__global__ __launch_bounds__(256) void k_gather_x(const float* __restrict__ xp,
                                                  const int* __restrict__ rowptr,
                                                  const int* __restrict__ srcs,
                                                  const float* __restrict__ dis,
                                                  float* __restrict__ aggx) {
    int tid = threadIdx.x;
    int g = tid >> 4, lane = tid & 15;
    int i = blockIdx.x * 16 + g;
    if (i >= NN) return;
    float di = dis[i];
    float acc = di * xp[i * 16 + lane];
    int beg = rowptr[i], end = rowptr[i + 1];
    int j = beg;
    for (; j + 1 < end; j += 2) {
        int s0 = srcs[j], s1 = srcs[j + 1];
        acc += dis[s0] * xp[s0 * 16 + lane];
        acc += dis[s1] * xp[s1 * 16 + lane];
    }
    if (j < end) {
        int s0 = srcs[j];
        acc += dis[s0] * xp[s0 * 16 + lane];
    }
    aggx[i * 16 + lane] = di * acc;
}

// A[i][f] = relu(b1[f] + sum_{k<9} aggx[i][k]*W1[k][f])
__global__ void k_xform9(const float* __restrict__ aggx, const float* __restrict__ W,
                         const float* __restrict__ b, float* __restrict__ out) {
    __shared__ float Ws[FIN * HD];
    int t = threadIdx.x;
    if (t < FIN * HD) Ws[t] = W[t];
    __syncthreads();
    long gtid = (long)blockIdx.x * 256 + t;
    int i = (int)(gtid >> 6);
    int f = (int)(gtid & 63);
    if (i >= NN) return;
    const float* row = aggx + (long)i * 16;
    float acc = b[f];
#pragma unroll
    for (int k = 0; k < FIN; ++k) acc += row[k] * Ws[k * HD + f];
    out[gtid] = acc > 0.f ? acc : 0.f;
}

// ---------------- layers 2/3: transform then gather ----------------

// out[i][f] = sum_k h[i][k] * W[k][f]  (no bias/relu here)
__global__ void k_xform64(const float* __restrict__ h, const float* __restrict__ W,
                          float* __restrict__ out) {
    __shared__ float Ws[HD * HD];
    int t = threadIdx.x;
    for (int k = t; k < HD * HD; k += 256) Ws[k] = W[k];
    __syncthreads();
    long gtid = (long)blockIdx.x * 256 + t;
    int i = (int)(gtid >> 6);
    int f = (int)(gtid & 63);
    if (i >= NN) return;
    const float* row = h + (long)i * HD;
    float acc = 0.f;
#pragma unroll
    for (int k = 0; k < HD; ++k) acc += row[k] * Ws[k * HD + f];
    out[gtid] = acc;
}

// wave per node: out[i][f] = relu(b[f] + di*( sum_e dis[s]*hW[s][f] + di*hW[i][f] ))
__global__ __launch_bounds__(256) void k_gather64(const float* __restrict__ hW,
                                                  const int* __restrict__ rowptr,
                                                  const int* __restrict__ srcs,
                                                  const float* __restrict__ dis,
                                                  const float* __restrict__ b,
                                                  float* __restrict__ out) {
    int tid = threadIdx.x;
    int w = tid >> 6, lane = tid & 63;
    int i = blockIdx.x * 4 + w;
    if (i >= NN) return;
    float di = dis[i];
    float acc = di * hW[(long)i * HD + lane];
    int beg = rowptr[i], end = rowptr[i + 1];
    int j = beg;
    for (; j + 1 < end; j += 2) {
        int s0 = srcs[j], s1 = srcs[j + 1];
        acc += dis[s0] * hW[(long)s0 * HD + lane];
        acc += dis[s1] * hW[(long)s1 * HD + lane];
    }
    if (j < end) {
        int s0 = srcs[j];
        acc += dis[s0] * hW[(long)s0 * HD + lane];
    }
    float v = di * acc + b[lane];
    out[(long)i * HD + lane] = v > 0.f ? v : 0.f;
}

// ---------------- pooling + MLP head ----------------

__global__ void k_zero(float* p, long n) {
    long i = (long)blockIdx.x * 256 + threadIdx.x;
    if (i < n) p[i] = 0.f;
}

__global__ void k_pool(const float* __restrict__ h, const int* __restrict__ batch,
                       float* __restrict__ z, float* __restrict__ cnt) {
    long gtid = (long)blockIdx.x * 256 + threadIdx.x;
    int i = (int)(gtid >> 6);
    int f = (int)(gtid & 63);
    if (i >= NN) return;
    int g = batch[i];
    atomicAdd(&z[(long)g * (HD + XD) + f], h[gtid]);
    if (f == 0) atomicAdd(&cnt[g], 1.0f);
}

__global__ void k_zfin(float* z, const float* __restrict__ cnt,
                       const float* __restrict__ extra) {
    int gtid = blockIdx.x * 256 + threadIdx.x;
    if (gtid >= NG * (HD + XD)) return;
    int g = gtid / (HD + XD);
    int f = gtid % (HD + XD);
    if (f < HD)
        z[gtid] = z[gtid] / fmaxf(cnt[g], 1.0f);
    else
        z[gtid] = extra[g * XD + (f - HD)];
}

template <int K, int M>
__global__ void k_mm(const float* __restrict__ in, const float* __restrict__ W,
                     const float* __restrict__ b, float* __restrict__ out) {
    int gtid = blockIdx.x * 256 + threadIdx.x;
    if (gtid >= NG * M) return;
    int g = gtid / M;
    int m = gtid % M;
    const float* row = in + (long)g * K;
    float acc = b[m];
#pragma unroll 8
    for (int k = 0; k < K; ++k) acc += row[k] * W[k * M + m];
    out[gtid] = acc;
}

template <int M>
__global__ void k_bn_relu(float* z, const float* __restrict__ gamma,
                          const float* __restrict__ beta) {
    int c = blockIdx.x;
    int t = threadIdx.x;
    __shared__ float s1[256], s2[256];
    float sum = 0.f, sumsq = 0.f;
    for (int g = t; g < NG; g += 256) {
        float v = z[(long)g * M + c];
        sum += v;
        sumsq += v * v;
    }
    s1[t] = sum;
    s2[t] = sumsq;
    __syncthreads();
    for (int o = 128; o > 0; o >>= 1) {
        if (t < o) {
            s1[t] += s1[t + o];
            s2[t] += s2[t + o];
        }
        __syncthreads();
    }
    float mean = s1[0] / (float)NG;
    float var = s2[0] / (float)NG - mean * mean;
    float scale = rsqrtf(var + BN_EPS) * gamma[c];
    float shift = beta[c] - mean * scale;
    for (int g = t; g < NG; g += 256) {
        float v = z[(long)g * M + c] * scale + shift;
        z[(long)g * M + c] = v > 0.f ? v : 0.f;
    }
}

__global__ void k_final(const float* __restrict__ z2, const float* __restrict__ W,
                        const float* __restrict__ b, float* __restrict__ out) {
    int g = blockIdx.x * 256 + threadIdx.x;
    if (g >= NG) return;
    const float* row = z2 + (long)g * 32;
    float acc = b[0];
#pragma unroll
    for (int k = 0; k < 32; ++k) acc += row[k] * W[k];
    out[g] = acc;
}

extern "C" void kernel_launch(void* const* d_in, const int* in_sizes, int n_in,
                              void* d_out, int out_size, void* d_ws, size_t ws_size,
                              hipStream_t stream) {
    const float* x = (const float*)d_in[0];
    const int* ei = (const int*)d_in[1];
    const int* batch = (const int*)d_in[2];
    const float* extra = (const float*)d_in[3];
    const float* W1 = (const float*)d_in[4];
    const float* b1 = (const float*)d_in[5];
    const float* W2 = (const float*)d_in[6];
    const float* b2 = (const float*)d_in[7];
    const float* W3 = (const float*)d_in[8];
    const float* b3 = (const float*)d_in[9];
    const float* Wm0 = (const float*)d_in[10];
    const float* bm0 = (const float*)d_in[11];
    const float* g0 = (const float*)d_in[12];
    const float* be0 = (const float*)d_in[13];
    const float* Wm1 = (const float*)d_in[14];
    const float* bm1 = (const float*)d_in[15];
    const float* g1 = (const float*)d_in[16];
    const float* be1 = (const float*)d_in[17];
    const float* Wm2 = (const float*)d_in[18];
    const float* bm2 = (const float*)d_in[19];
    const float* g2 = (const float*)d_in[20];
    const float* be2 = (const float*)d_in[21];
    const float* Wm3 = (const float*)d_in[22];
    const float* bm3 = (const float*)d_in[23];

    const int* src = ei;
    const int* dst = ei + NE;

    // workspace layout
    int* rowptr = (int*)d_ws;                 // 100352
    int* cursor = rowptr + 100352;            // 100352
    int* srcs = cursor + 100352;              // NE
    float* dis = (float*)(srcs + NE);         // 100352
    float* xp = dis + 100352;                 // NN*16
    float* aggx = xp + (long)NN * 16;         // NN*16
    float* A = aggx + (long)NN * 16;          // NN*64
    float* B = A + (long)NN * HD;             // NN*64
    float* z = B + (long)NN * HD;             // NG*96
    float* cnt = z + NG * (HD + XD);          // NG
    float* t0 = cnt + NG;                     // NG*128
    float* t1 = t0 + NG * 128;                // NG*64
    float* t2 = t1 + NG * 64;                 // NG*32

    const long NF = (long)NN * HD;
    dim3 bNF((unsigned)((NF + 255) / 256));
    unsigned bE = (NE + 255) / 256;
    unsigned bN = (NN + 255) / 256;

    // ---- CSR build (+ dis) ----
    k_zeroi<<<bN, 256, 0, stream>>>(cursor, NN);
    k_count<<<bE, 256, 0, stream>>>(dst, cursor);
    k_dis<<<bN, 256, 0, stream>>>(cursor, dis);
    k_scan<<<1, 1024, 0, stream>>>(cursor, rowptr);
    k_zeroi<<<bN, 256, 0, stream>>>(cursor, NN);
    k_scatter<<<bE, 256, 0, stream>>>(src, dst, rowptr, cursor, srcs);

    // ---- layer 1 (aggregate input, then transform) ----
    k_padx<<<(NN * 16 + 255) / 256, 256, 0, stream>>>(x, xp);
    k_gather_x<<<(NN + 15) / 16, 256, 0, stream>>>(xp, rowptr, srcs, dis, aggx);
    k_xform9<<<bNF, 256, 0, stream>>>(aggx, W1, b1, A);  // A = h1

    // ---- layer 2 ----
    k_xform64<<<bNF, 256, 0, stream>>>(A, W2, B);        // B = h1@W2
    k_gather64<<<(NN + 3) / 4, 256, 0, stream>>>(B, rowptr, srcs, dis, b2, A);  // A = h2

    // ---- layer 3 ----
    k_xform64<<<bNF, 256, 0, stream>>>(A, W3, B);        // B = h2@W3
    k_gather64<<<(NN + 3) / 4, 256, 0, stream>>>(B, rowptr, srcs, dis, b3, A);  // A = h3

    // ---- pooling ----
    long zlen = (long)NG * (HD + XD) + NG;
    k_zero<<<(unsigned)((zlen + 255) / 256), 256, 0, stream>>>(z, zlen);
    k_pool<<<bNF, 256, 0, stream>>>(A, batch, z, cnt);
    k_zfin<<<(NG * (HD + XD) + 255) / 256, 256, 0, stream>>>(z, cnt, extra);

    // ---- MLP head ----
    k_mm<96, 128><<<(NG * 128 + 255) / 256, 256, 0, stream>>>(z, Wm0, bm0, t0);
    k_bn_relu<128><<<128, 256, 0, stream>>>(t0, g0, be0);
    k_mm<128, 64><<<(NG * 64 + 255) / 256, 256, 0, stream>>>(t0, Wm1, bm1, t1);
    k_bn_relu<64><<<64, 256, 0, stream>>>(t1, g1, be1);
    k_mm<64, 32><<<(NG * 32 + 255) / 256, 256, 0, stream>>>(t1, Wm2, bm2, t2);
    k_bn_relu<32><<<32, 256, 0, stream>>>(t2, g2, be2);
    k_final<<<(NG + 255) / 256, 256, 0, stream>>>(t2, Wm3, bm3, (float*)d_out);
}

// Round 3
// 795.874 us; speedup vs baseline: 3.2638x; 1.3283x over previous
//
#include <hip/hip_runtime.h>

#define NN 100000
#define NE 3200000
#define NG 2048
#define FIN 9
#define HD 64
#define XD 32
#define BN_EPS 1e-5f

__device__ __forceinline__ unsigned f2bf(float f) {
    unsigned u = __float_as_uint(f);
    return (u + 0x7fffu + ((u >> 16) & 1u)) >> 16;
}
__device__ __forceinline__ unsigned pack2bf(float lo, float hi) {
    return f2bf(lo) | (f2bf(hi) << 16);
}
__device__ __forceinline__ float bflo(unsigned u) { return __uint_as_float(u << 16); }
__device__ __forceinline__ float bfhi(unsigned u) { return __uint_as_float(u & 0xffff0000u); }

// ---------------- CSR build ----------------

__global__ void k_zeroi(int* p, int n) {
    int i = blockIdx.x * 256 + threadIdx.x;
    if (i < n) p[i] = 0;
}

__global__ void k_count(const int* __restrict__ dst, int* __restrict__ cnt) {
    int e = blockIdx.x * 256 + threadIdx.x;
    if (e < NE) atomicAdd(&cnt[dst[e]], 1);
}

__global__ void k_dis(const int* __restrict__ cnt, float* __restrict__ dis) {
    int i = blockIdx.x * 256 + threadIdx.x;
    if (i < NN) dis[i] = rsqrtf((float)cnt[i] + 1.0f);  // +1 self loop
}

__global__ __launch_bounds__(1024) void k_scan(const int* __restrict__ cnt,
                                               int* __restrict__ rowptr) {
    __shared__ int wsum[16];
    __shared__ int carry_s;
    int tid = threadIdx.x, lane = tid & 63, wid = tid >> 6;
    if (tid == 0) { carry_s = 0; rowptr[0] = 0; }
    __syncthreads();
    for (int base = 0; base < NN; base += 4096) {
        int i0 = base + tid * 4;
        int v0 = (i0 + 0 < NN) ? cnt[i0 + 0] : 0;
        int v1 = (i0 + 1 < NN) ? cnt[i0 + 1] : 0;
        int v2 = (i0 + 2 < NN) ? cnt[i0 + 2] : 0;
        int v3 = (i0 + 3 < NN) ? cnt[i0 + 3] : 0;
        int s = v0 + v1 + v2 + v3;
        int x = s;
        for (int off = 1; off < 64; off <<= 1) {
            int y = __shfl_up(x, off, 64);
            if (lane >= off) x += y;
        }
        if (lane == 63) wsum[wid] = x;
        __syncthreads();
        if (wid == 0 && lane < 16) {
            int y = wsum[lane];
            for (int off = 1; off < 16; off <<= 1) {
                int z2 = __shfl_up(y, off, 16);
                if (lane >= off) y += z2;
            }
            wsum[lane] = y;
        }
        __syncthreads();
        int wofs = (wid > 0) ? wsum[wid - 1] : 0;
        int total = wsum[15];
        int p = x - s + wofs + carry_s;
        if (i0 + 0 < NN) { p += v0; rowptr[i0 + 1] = p; }
        if (i0 + 1 < NN) { p += v1; rowptr[i0 + 2] = p; }
        if (i0 + 2 < NN) { p += v2; rowptr[i0 + 3] = p; }
        if (i0 + 3 < NN) { p += v3; rowptr[i0 + 4] = p; }
        __syncthreads();
        if (tid == 0) carry_s += total;
        __syncthreads();
    }
}

__global__ void k_scatter(const int* __restrict__ src, const int* __restrict__ dst,
                          const int* __restrict__ rowptr, int* __restrict__ cursor,
                          int* __restrict__ srcs) {
    int e = blockIdx.x * 256 + threadIdx.x;
    if (e >= NE) return;
    int d = dst[e];
    int pos = rowptr[d] + atomicAdd(&cursor[d], 1);
    srcs[pos] = src[e];
}

// ---------------- layer 1 ----------------

// xpd16[i][u] = pack2bf(dis[i]*x[i][2u], dis[i]*x[i][2u+1]), padded to 16 feats
__global__ void k_padx16(const float* __restrict__ x, const float* __restrict__ dis,
                         unsigned* __restrict__ xpd) {
    int gtid = blockIdx.x * 256 + threadIdx.x;
    if (gtid >= NN * 8) return;
    int i = gtid >> 3, u = gtid & 7;
    float d = dis[i];
    int f0 = 2 * u, f1 = 2 * u + 1;
    float a = (f0 < FIN) ? d * x[i * FIN + f0] : 0.f;
    float b = (f1 < FIN) ? d * x[i * FIN + f1] : 0.f;
    xpd[gtid] = pack2bf(a, b);
}

// 8 lanes per node: aggx[i] = di * ( sum_e xpd[s] + xpd[i] )  (fp32 out, [N,16])
__global__ __launch_bounds__(256) void k_gather_x8(const unsigned* __restrict__ xpd,
                                                   const int* __restrict__ rowptr,
                                                   const int* __restrict__ srcs,
                                                   const float* __restrict__ dis,
                                                   float* __restrict__ aggx) {
    int tid = threadIdx.x;
    int i = blockIdx.x * 32 + (tid >> 3);
    int lane = tid & 7;
    if (i >= NN) return;
    float di = dis[i];
    unsigned u = xpd[i * 8 + lane];
    float a0 = bflo(u), a1 = bfhi(u);
    int beg = rowptr[i], end = rowptr[i + 1];
    int j = beg;
    for (; j + 1 < end; j += 2) {
        int s0 = srcs[j], s1 = srcs[j + 1];
        unsigned u0 = xpd[s0 * 8 + lane];
        unsigned u1 = xpd[s1 * 8 + lane];
        a0 += bflo(u0) + bflo(u1);
        a1 += bfhi(u0) + bfhi(u1);
    }
    if (j < end) {
        int s0 = srcs[j];
        unsigned u0 = xpd[s0 * 8 + lane];
        a0 += bflo(u0);
        a1 += bfhi(u0);
    }
    float2 r = make_float2(di * a0, di * a1);
    *reinterpret_cast<float2*>(aggx + (long)i * 16 + lane * 2) = r;
}

// A[i][f] = relu(b1[f] + sum_{k<9} aggx[i][k]*W1[k][f])
__global__ void k_xform9(const float* __restrict__ aggx, const float* __restrict__ W,
                         const float* __restrict__ b, float* __restrict__ out) {
    __shared__ float Ws[FIN * HD];
    int t = threadIdx.x;
    if (t < FIN * HD) Ws[t] = W[t];
    __syncthreads();
    long gtid = (long)blockIdx.x * 256 + t;
    int i = (int)(gtid >> 6);
    int f = (int)(gtid & 63);
    if (i >= NN) return;
    const float* row = aggx + (long)i * 16;
    float acc = b[f];
#pragma unroll
    for (int k = 0; k < FIN; ++k) acc += row[k] * Ws[k * HD + f];
    out[gtid] = acc > 0.f ? acc : 0.f;
}

// ---------------- layers 2/3 ----------------

// out16[i][u] = pack2bf( dis[i] * (h[i]@W)[2u], dis[i] * (h[i]@W)[2u+1] )
__global__ void k_xform64d(const float* __restrict__ h, const float* __restrict__ W,
                           const float* __restrict__ dis, unsigned* __restrict__ out16) {
    __shared__ float Ws[HD * HD];
    int t = threadIdx.x;
    for (int k = t; k < HD * HD; k += 256) Ws[k] = W[k];
    __syncthreads();
    long gtid = (long)blockIdx.x * 256 + t;
    int i = (int)(gtid >> 5);
    int u = (int)(gtid & 31);
    if (i >= NN) return;
    const float* row = h + (long)i * HD;
    int f0 = 2 * u;
    float a0 = 0.f, a1 = 0.f;
#pragma unroll
    for (int k = 0; k < HD; ++k) {
        float r = row[k];
        a0 += r * Ws[k * HD + f0];
        a1 += r * Ws[k * HD + f0 + 1];
    }
    float d = dis[i];
    out16[gtid] = pack2bf(d * a0, d * a1);
}

// 32 lanes per node: out[i][f] = relu(b[f] + di*( sum_e hWd[s][f] + hWd[i][f] ))
// if POOL: also atomicAdd into z[batch[i]*96 + f]
template <int POOL>
__global__ __launch_bounds__(256) void k_gather64b(const unsigned* __restrict__ hWd,
                                                   const int* __restrict__ rowptr,
                                                   const int* __restrict__ srcs,
                                                   const float* __restrict__ dis,
                                                   const float* __restrict__ b,
                                                   const int* __restrict__ batch,
                                                   float* __restrict__ z,
                                                   float* __restrict__ out) {
    int tid = threadIdx.x;
    int i = blockIdx.x * 8 + (tid >> 5);
    int lane = tid & 31;
    if (i >= NN) return;
    float di = dis[i];
    unsigned u = hWd[(long)i * 32 + lane];
    float a0 = bflo(u), a1 = bfhi(u);
    int beg = rowptr[i], end = rowptr[i + 1];
    int j = beg;
    for (; j + 1 < end; j += 2) {
        int s0 = srcs[j], s1 = srcs[j + 1];
        unsigned u0 = hWd[(long)s0 * 32 + lane];
        unsigned u1 = hWd[(long)s1 * 32 + lane];
        a0 += bflo(u0) + bflo(u1);
        a1 += bfhi(u0) + bfhi(u1);
    }
    if (j < end) {
        int s0 = srcs[j];
        unsigned u0 = hWd[(long)s0 * 32 + lane];
        a0 += bflo(u0);
        a1 += bfhi(u0);
    }
    int f0 = 2 * lane;
    float v0 = di * a0 + b[f0];
    float v1 = di * a1 + b[f0 + 1];
    v0 = v0 > 0.f ? v0 : 0.f;
    v1 = v1 > 0.f ? v1 : 0.f;
    if (POOL) {
        int g = batch[i];
        atomicAdd(&z[(long)g * (HD + XD) + f0], v0);
        atomicAdd(&z[(long)g * (HD + XD) + f0 + 1], v1);
    } else {
        *reinterpret_cast<float2*>(out + (long)i * HD + f0) = make_float2(v0, v1);
    }
}

// ---------------- pooling + MLP head ----------------

__global__ void k_zero(float* p, long n) {
    long i = (long)blockIdx.x * 256 + threadIdx.x;
    if (i < n) p[i] = 0.f;
}

__global__ void k_cnt(const int* __restrict__ batch, float* __restrict__ cnt) {
    int i = blockIdx.x * 256 + threadIdx.x;
    if (i < NN) atomicAdd(&cnt[batch[i]], 1.0f);
}

__global__ void k_zfin(float* z, const float* __restrict__ cnt,
                       const float* __restrict__ extra) {
    int gtid = blockIdx.x * 256 + threadIdx.x;
    if (gtid >= NG * (HD + XD)) return;
    int g = gtid / (HD + XD);
    int f = gtid % (HD + XD);
    if (f < HD)
        z[gtid] = z[gtid] / fmaxf(cnt[g], 1.0f);
    else
        z[gtid] = extra[g * XD + (f - HD)];
}

template <int K, int M>
__global__ void k_mm(const float* __restrict__ in, const float* __restrict__ W,
                     const float* __restrict__ b, float* __restrict__ out) {
    int gtid = blockIdx.x * 256 + threadIdx.x;
    if (gtid >= NG * M) return;
    int g = gtid / M;
    int m = gtid % M;
    const float* row = in + (long)g * K;
    float acc = b[m];
#pragma unroll 8
    for (int k = 0; k < K; ++k) acc += row[k] * W[k * M + m];
    out[gtid] = acc;
}

template <int M>
__global__ void k_bn_relu(float* z, const float* __restrict__ gamma,
                          const float* __restrict__ beta) {
    int c = blockIdx.x;
    int t = threadIdx.x;
    __shared__ float s1[256], s2[256];
    float sum = 0.f, sumsq = 0.f;
    for (int g = t; g < NG; g += 256) {
        float v = z[(long)g * M + c];
        sum += v;
        sumsq += v * v;
    }
    s1[t] = sum;
    s2[t] = sumsq;
    __syncthreads();
    for (int o = 128; o > 0; o >>= 1) {
        if (t < o) {
            s1[t] += s1[t + o];
            s2[t] += s2[t + o];
        }
        __syncthreads();
    }
    float mean = s1[0] / (float)NG;
    float var = s2[0] / (float)NG - mean * mean;
    float scale = rsqrtf(var + BN_EPS) * gamma[c];
    float shift = beta[c] - mean * scale;
    for (int g = t; g < NG; g += 256) {
        float v = z[(long)g * M + c] * scale + shift;
        z[(long)g * M + c] = v > 0.f ? v : 0.f;
    }
}

__global__ void k_final(const float* __restrict__ z2, const float* __restrict__ W,
                        const float* __restrict__ b, float* __restrict__ out) {
    int g = blockIdx.x * 256 + threadIdx.x;
    if (g >= NG) return;
    const float* row = z2 + (long)g * 32;
    float acc = b[0];
#pragma unroll
    for (int k = 0; k < 32; ++k) acc += row[k] * W[k];
    out[g] = acc;
}

extern "C" void kernel_launch(void* const* d_in, const int* in_sizes, int n_in,
                              void* d_out, int out_size, void* d_ws, size_t ws_size,
                              hipStream_t stream) {
    const float* x = (const float*)d_in[0];
    const int* ei = (const int*)d_in[1];
    const int* batch = (const int*)d_in[2];
    const float* extra = (const float*)d_in[3];
    const float* W1 = (const float*)d_in[4];
    const float* b1 = (const float*)d_in[5];
    const float* W2 = (const float*)d_in[6];
    const float* b2 = (const float*)d_in[7];
    const float* W3 = (const float*)d_in[8];
    const float* b3 = (const float*)d_in[9];
    const float* Wm0 = (const float*)d_in[10];
    const float* bm0 = (const float*)d_in[11];
    const float* g0 = (const float*)d_in[12];
    const float* be0 = (const float*)d_in[13];
    const float* Wm1 = (const float*)d_in[14];
    const float* bm1 = (const float*)d_in[15];
    const float* Wm2 = (const float*)d_in[18];
    const float* bm2 = (const float*)d_in[19];
    const float* g1 = (const float*)d_in[16];
    const float* be1 = (const float*)d_in[17];
    const float* g2 = (const float*)d_in[20];
    const float* be2 = (const float*)d_in[21];
    const float* Wm3 = (const float*)d_in[22];
    const float* bm3 = (const float*)d_in[23];

    const int* src = ei;
    const int* dst = ei + NE;

    // workspace layout
    int* rowptr = (int*)d_ws;                 // 100352
    int* cursor = rowptr + 100352;            // 100352
    int* srcs = cursor + 100352;              // NE
    float* dis = (float*)(srcs + NE);         // 100352
    unsigned* xpd = (unsigned*)(dis + 100352);// NN*8
    float* aggx = (float*)(xpd + (long)NN * 8);  // NN*16
    float* A = aggx + (long)NN * 16;          // NN*64
    unsigned* B16 = (unsigned*)(A + (long)NN * HD);  // NN*32
    float* z = (float*)(B16 + (long)NN * 32); // NG*96
    float* cnt = z + NG * (HD + XD);          // NG
    float* t0 = cnt + NG;                     // NG*128
    float* t1 = t0 + NG * 128;                // NG*64
    float* t2 = t1 + NG * 64;                 // NG*32

    unsigned bE = (NE + 255) / 256;
    unsigned bN = (NN + 255) / 256;
    unsigned bN32 = (NN * 32 + 255) / 256;
    unsigned bN64 = (NN * 64 + 255) / 256;
    unsigned bG8 = (NN + 7) / 8;

    // ---- CSR build (+ dis) ----
    k_zeroi<<<bN, 256, 0, stream>>>(cursor, NN);
    k_count<<<bE, 256, 0, stream>>>(dst, cursor);
    k_dis<<<bN, 256, 0, stream>>>(cursor, dis);
    k_scan<<<1, 1024, 0, stream>>>(cursor, rowptr);
    k_zeroi<<<bN, 256, 0, stream>>>(cursor, NN);
    k_scatter<<<bE, 256, 0, stream>>>(src, dst, rowptr, cursor, srcs);

    // zero pooled buffers early (layer-3 gather pools into them)
    long zlen = (long)NG * (HD + XD) + NG;
    k_zero<<<(unsigned)((zlen + 255) / 256), 256, 0, stream>>>(z, zlen);

    // ---- layer 1 ----
    k_padx16<<<(NN * 8 + 255) / 256, 256, 0, stream>>>(x, dis, xpd);
    k_gather_x8<<<(NN + 31) / 32, 256, 0, stream>>>(xpd, rowptr, srcs, dis, aggx);
    k_xform9<<<bN64, 256, 0, stream>>>(aggx, W1, b1, A);  // A = h1

    // ---- layer 2 ----
    k_xform64d<<<bN32, 256, 0, stream>>>(A, W2, dis, B16);
    k_gather64b<0><<<bG8, 256, 0, stream>>>(B16, rowptr, srcs, dis, b2, batch, z, A);  // A = h2

    // ---- layer 3 (pool fused) ----
    k_xform64d<<<bN32, 256, 0, stream>>>(A, W3, dis, B16);
    k_gather64b<1><<<bG8, 256, 0, stream>>>(B16, rowptr, srcs, dis, b3, batch, z, A);

    // ---- pooling finalize ----
    k_cnt<<<bN, 256, 0, stream>>>(batch, cnt);
    k_zfin<<<(NG * (HD + XD) + 255) / 256, 256, 0, stream>>>(z, cnt, extra);

    // ---- MLP head ----
    k_mm<96, 128><<<(NG * 128 + 255) / 256, 256, 0, stream>>>(z, Wm0, bm0, t0);
    k_bn_relu<128><<<128, 256, 0, stream>>>(t0, g0, be0);
    k_mm<128, 64><<<(NG * 64 + 255) / 256, 256, 0, stream>>>(t0, Wm1, bm1, t1);
    k_bn_relu<64><<<64, 256, 0, stream>>>(t1, g1, be1);
    k_mm<64, 32><<<(NG * 32 + 255) / 256, 256, 0, stream>>>(t1, Wm2, bm2, t2);
    k_bn_relu<32><<<32, 256, 0, stream>>>(t2, g2, be2);
    k_final<<<(NG + 255) / 256, 256, 0, stream>>>(t2, Wm3, bm3, (float*)d_out);
}

// Round 4
// 773.063 us; speedup vs baseline: 3.3601x; 1.0295x over previous
//
#include <hip/hip_runtime.h>

#define NN 100000
#define NE 3200000
#define NG 2048
#define FIN 9
#define HD 64
#define XD 32
#define BN_EPS 1e-5f
#define RNG 12500  // NN/8 per dst-range group

__device__ __forceinline__ unsigned f2bf(float f) {
    unsigned u = __float_as_uint(f);
    return (u + 0x7fffu + ((u >> 16) & 1u)) >> 16;
}
__device__ __forceinline__ unsigned pack2bf(float lo, float hi) {
    return f2bf(lo) | (f2bf(hi) << 16);
}
__device__ __forceinline__ float bflo(unsigned u) { return __uint_as_float(u << 16); }
__device__ __forceinline__ float bfhi(unsigned u) { return __uint_as_float(u & 0xffff0000u); }

// ---------------- CSR build ----------------

__global__ void k_zeroi(int* p, int n) {
    int i = blockIdx.x * 256 + threadIdx.x;
    if (i < n) p[i] = 0;
}

__global__ void k_count(const int* __restrict__ dst, int* __restrict__ cnt) {
    int e = blockIdx.x * 256 + threadIdx.x;
    if (e < NE) atomicAdd(&cnt[dst[e]], 1);
}

__global__ void k_dis(const int* __restrict__ cnt, float* __restrict__ dis) {
    int i = blockIdx.x * 256 + threadIdx.x;
    if (i < NN) dis[i] = rsqrtf((float)cnt[i] + 1.0f);  // +1 self loop
}

__global__ __launch_bounds__(1024) void k_scan(const int* __restrict__ cnt,
                                               int* __restrict__ rowptr) {
    __shared__ int wsum[16];
    __shared__ int carry_s;
    int tid = threadIdx.x, lane = tid & 63, wid = tid >> 6;
    if (tid == 0) { carry_s = 0; rowptr[0] = 0; }
    __syncthreads();
    for (int base = 0; base < NN; base += 4096) {
        int i0 = base + tid * 4;
        int v0 = (i0 + 0 < NN) ? cnt[i0 + 0] : 0;
        int v1 = (i0 + 1 < NN) ? cnt[i0 + 1] : 0;
        int v2 = (i0 + 2 < NN) ? cnt[i0 + 2] : 0;
        int v3 = (i0 + 3 < NN) ? cnt[i0 + 3] : 0;
        int s = v0 + v1 + v2 + v3;
        int x = s;
        for (int off = 1; off < 64; off <<= 1) {
            int y = __shfl_up(x, off, 64);
            if (lane >= off) x += y;
        }
        if (lane == 63) wsum[wid] = x;
        __syncthreads();
        if (wid == 0 && lane < 16) {
            int y = wsum[lane];
            for (int off = 1; off < 16; off <<= 1) {
                int z2 = __shfl_up(y, off, 16);
                if (lane >= off) y += z2;
            }
            wsum[lane] = y;
        }
        __syncthreads();
        int wofs = (wid > 0) ? wsum[wid - 1] : 0;
        int total = wsum[15];
        int p = x - s + wofs + carry_s;
        if (i0 + 0 < NN) { p += v0; rowptr[i0 + 1] = p; }
        if (i0 + 1 < NN) { p += v1; rowptr[i0 + 2] = p; }
        if (i0 + 2 < NN) { p += v2; rowptr[i0 + 3] = p; }
        if (i0 + 3 < NN) { p += v3; rowptr[i0 + 4] = p; }
        __syncthreads();
        if (tid == 0) carry_s += total;
        __syncthreads();
    }
}

// dst-range-partitioned scatter: group g (= blockIdx&7, XCD-aligned under the
// measured round-robin mapping) scans ALL edges, writes only dst in
// [g*RNG, (g+1)*RNG). Keeps each srcs cache line dirty in one XCD's L2 only.
__global__ __launch_bounds__(256) void k_scatter_r(const int* __restrict__ src,
                                                   const int* __restrict__ dst,
                                                   const int* __restrict__ rowptr,
                                                   int* __restrict__ cursor,
                                                   int* __restrict__ srcs,
                                                   int nblocks) {
    int g = blockIdx.x & 7;
    int gb = blockIdx.x >> 3;           // block index within group
    int nb = nblocks >> 3;              // blocks per group
    int lo = g * RNG, hi = lo + RNG;
    for (int e = gb * 256 + threadIdx.x; e < NE; e += nb * 256) {
        int d = dst[e];
        if (d >= lo && d < hi) {
            int pos = rowptr[d] + atomicAdd(&cursor[d], 1);
            srcs[pos] = src[e];
        }
    }
}

// ---------------- layer 1 ----------------

__global__ void k_padx16(const float* __restrict__ x, const float* __restrict__ dis,
                         unsigned* __restrict__ xpd) {
    int gtid = blockIdx.x * 256 + threadIdx.x;
    if (gtid >= NN * 8) return;
    int i = gtid >> 3, u = gtid & 7;
    float d = dis[i];
    int f0 = 2 * u, f1 = 2 * u + 1;
    float a = (f0 < FIN) ? d * x[i * FIN + f0] : 0.f;
    float b = (f1 < FIN) ? d * x[i * FIN + f1] : 0.f;
    xpd[gtid] = pack2bf(a, b);
}

__global__ __launch_bounds__(256) void k_gather_x8(const unsigned* __restrict__ xpd,
                                                   const int* __restrict__ rowptr,
                                                   const int* __restrict__ srcs,
                                                   const float* __restrict__ dis,
                                                   float* __restrict__ aggx) {
    int tid = threadIdx.x;
    int i = blockIdx.x * 32 + (tid >> 3);
    int lane = tid & 7;
    if (i >= NN) return;
    float di = dis[i];
    unsigned u = xpd[i * 8 + lane];
    float a0 = bflo(u), a1 = bfhi(u);
    int beg = rowptr[i], end = rowptr[i + 1];
    int j = beg;
    for (; j + 1 < end; j += 2) {
        int s0 = srcs[j], s1 = srcs[j + 1];
        unsigned u0 = xpd[s0 * 8 + lane];
        unsigned u1 = xpd[s1 * 8 + lane];
        a0 += bflo(u0) + bflo(u1);
        a1 += bfhi(u0) + bfhi(u1);
    }
    if (j < end) {
        int s0 = srcs[j];
        unsigned u0 = xpd[s0 * 8 + lane];
        a0 += bflo(u0);
        a1 += bfhi(u0);
    }
    float2 r = make_float2(di * a0, di * a1);
    *reinterpret_cast<float2*>(aggx + (long)i * 16 + lane * 2) = r;
}

__global__ void k_xform9(const float* __restrict__ aggx, const float* __restrict__ W,
                         const float* __restrict__ b, float* __restrict__ out) {
    __shared__ float Ws[FIN * HD];
    int t = threadIdx.x;
    if (t < FIN * HD) Ws[t] = W[t];
    __syncthreads();
    long gtid = (long)blockIdx.x * 256 + t;
    int i = (int)(gtid >> 6);
    int f = (int)(gtid & 63);
    if (i >= NN) return;
    const float* row = aggx + (long)i * 16;
    float acc = b[f];
#pragma unroll
    for (int k = 0; k < FIN; ++k) acc += row[k] * Ws[k * HD + f];
    out[gtid] = acc > 0.f ? acc : 0.f;
}

// ---------------- layers 2/3 ----------------

__global__ void k_xform64d(const float* __restrict__ h, const float* __restrict__ W,
                           const float* __restrict__ dis, unsigned* __restrict__ out16) {
    __shared__ float Ws[HD * HD];
    int t = threadIdx.x;
    for (int k = t; k < HD * HD; k += 256) Ws[k] = W[k];
    __syncthreads();
    long gtid = (long)blockIdx.x * 256 + t;
    int i = (int)(gtid >> 5);
    int u = (int)(gtid & 31);
    if (i >= NN) return;
    const float* row = h + (long)i * HD;
    int f0 = 2 * u;
    float a0 = 0.f, a1 = 0.f;
#pragma unroll
    for (int k = 0; k < HD; ++k) {
        float r = row[k];
        a0 += r * Ws[k * HD + f0];
        a1 += r * Ws[k * HD + f0 + 1];
    }
    float d = dis[i];
    out16[gtid] = pack2bf(d * a0, d * a1);
}

template <int POOL>
__global__ __launch_bounds__(256) void k_gather64b(const unsigned* __restrict__ hWd,
                                                   const int* __restrict__ rowptr,
                                                   const int* __restrict__ srcs,
                                                   const float* __restrict__ dis,
                                                   const float* __restrict__ b,
                                                   const int* __restrict__ batch,
                                                   float* __restrict__ z,
                                                   float* __restrict__ out) {
    int tid = threadIdx.x;
    int i = blockIdx.x * 8 + (tid >> 5);
    int lane = tid & 31;
    if (i >= NN) return;
    float di = dis[i];
    unsigned u = hWd[(long)i * 32 + lane];
    float a0 = bflo(u), a1 = bfhi(u);
    int beg = rowptr[i], end = rowptr[i + 1];
    int j = beg;
    for (; j + 1 < end; j += 2) {
        int s0 = srcs[j], s1 = srcs[j + 1];
        unsigned u0 = hWd[(long)s0 * 32 + lane];
        unsigned u1 = hWd[(long)s1 * 32 + lane];
        a0 += bflo(u0) + bflo(u1);
        a1 += bfhi(u0) + bfhi(u1);
    }
    if (j < end) {
        int s0 = srcs[j];
        unsigned u0 = hWd[(long)s0 * 32 + lane];
        a0 += bflo(u0);
        a1 += bfhi(u0);
    }
    int f0 = 2 * lane;
    float v0 = di * a0 + b[f0];
    float v1 = di * a1 + b[f0 + 1];
    v0 = v0 > 0.f ? v0 : 0.f;
    v1 = v1 > 0.f ? v1 : 0.f;
    if (POOL) {
        int g = batch[i];
        atomicAdd(&z[(long)g * (HD + XD) + f0], v0);
        atomicAdd(&z[(long)g * (HD + XD) + f0 + 1], v1);
    } else {
        *reinterpret_cast<float2*>(out + (long)i * HD + f0) = make_float2(v0, v1);
    }
}

// ---------------- pooling + MLP head ----------------

__global__ void k_zero(float* p, long n) {
    long i = (long)blockIdx.x * 256 + threadIdx.x;
    if (i < n) p[i] = 0.f;
}

__global__ void k_cnt(const int* __restrict__ batch, float* __restrict__ cnt) {
    int i = blockIdx.x * 256 + threadIdx.x;
    if (i < NN) atomicAdd(&cnt[batch[i]], 1.0f);
}

__global__ void k_zfin(float* z, const float* __restrict__ cnt,
                       const float* __restrict__ extra) {
    int gtid = blockIdx.x * 256 + threadIdx.x;
    if (gtid >= NG * (HD + XD)) return;
    int g = gtid / (HD + XD);
    int f = gtid % (HD + XD);
    if (f < HD)
        z[gtid] = z[gtid] / fmaxf(cnt[g], 1.0f);
    else
        z[gtid] = extra[g * XD + (f - HD)];
}

template <int K, int M>
__global__ void k_mm(const float* __restrict__ in, const float* __restrict__ W,
                     const float* __restrict__ b, float* __restrict__ out) {
    int gtid = blockIdx.x * 256 + threadIdx.x;
    if (gtid >= NG * M) return;
    int g = gtid / M;
    int m = gtid % M;
    const float* row = in + (long)g * K;
    float acc = b[m];
#pragma unroll 8
    for (int k = 0; k < K; ++k) acc += row[k] * W[k * M + m];
    out[gtid] = acc;
}

template <int M>
__global__ void k_bn_relu(float* z, const float* __restrict__ gamma,
                          const float* __restrict__ beta) {
    int c = blockIdx.x;
    int t = threadIdx.x;
    __shared__ float s1[256], s2[256];
    float sum = 0.f, sumsq = 0.f;
    for (int g = t; g < NG; g += 256) {
        float v = z[(long)g * M + c];
        sum += v;
        sumsq += v * v;
    }
    s1[t] = sum;
    s2[t] = sumsq;
    __syncthreads();
    for (int o = 128; o > 0; o >>= 1) {
        if (t < o) {
            s1[t] += s1[t + o];
            s2[t] += s2[t + o];
        }
        __syncthreads();
    }
    float mean = s1[0] / (float)NG;
    float var = s2[0] / (float)NG - mean * mean;
    float scale = rsqrtf(var + BN_EPS) * gamma[c];
    float shift = beta[c] - mean * scale;
    for (int g = t; g < NG; g += 256) {
        float v = z[(long)g * M + c] * scale + shift;
        z[(long)g * M + c] = v > 0.f ? v : 0.f;
    }
}

__global__ void k_final(const float* __restrict__ z2, const float* __restrict__ W,
                        const float* __restrict__ b, float* __restrict__ out) {
    int g = blockIdx.x * 256 + threadIdx.x;
    if (g >= NG) return;
    const float* row = z2 + (long)g * 32;
    float acc = b[0];
#pragma unroll
    for (int k = 0; k < 32; ++k) acc += row[k] * W[k];
    out[g] = acc;
}

extern "C" void kernel_launch(void* const* d_in, const int* in_sizes, int n_in,
                              void* d_out, int out_size, void* d_ws, size_t ws_size,
                              hipStream_t stream) {
    const float* x = (const float*)d_in[0];
    const int* ei = (const int*)d_in[1];
    const int* batch = (const int*)d_in[2];
    const float* extra = (const float*)d_in[3];
    const float* W1 = (const float*)d_in[4];
    const float* b1 = (const float*)d_in[5];
    const float* W2 = (const float*)d_in[6];
    const float* b2 = (const float*)d_in[7];
    const float* W3 = (const float*)d_in[8];
    const float* b3 = (const float*)d_in[9];
    const float* Wm0 = (const float*)d_in[10];
    const float* bm0 = (const float*)d_in[11];
    const float* g0 = (const float*)d_in[12];
    const float* be0 = (const float*)d_in[13];
    const float* Wm1 = (const float*)d_in[14];
    const float* bm1 = (const float*)d_in[15];
    const float* g1 = (const float*)d_in[16];
    const float* be1 = (const float*)d_in[17];
    const float* Wm2 = (const float*)d_in[18];
    const float* bm2 = (const float*)d_in[19];
    const float* g2 = (const float*)d_in[20];
    const float* be2 = (const float*)d_in[21];
    const float* Wm3 = (const float*)d_in[22];
    const float* bm3 = (const float*)d_in[23];

    const int* src = ei;
    const int* dst = ei + NE;

    // workspace layout
    int* rowptr = (int*)d_ws;                 // 100352
    int* cursor = rowptr + 100352;            // 100352
    int* srcs = cursor + 100352;              // NE
    float* dis = (float*)(srcs + NE);         // 100352
    unsigned* xpd = (unsigned*)(dis + 100352);// NN*8
    float* aggx = (float*)(xpd + (long)NN * 8);  // NN*16
    float* A = aggx + (long)NN * 16;          // NN*64
    unsigned* B16 = (unsigned*)(A + (long)NN * HD);  // NN*32
    float* z = (float*)(B16 + (long)NN * 32); // NG*96
    float* cnt = z + NG * (HD + XD);          // NG
    float* t0 = cnt + NG;                     // NG*128
    float* t1 = t0 + NG * 128;                // NG*64
    float* t2 = t1 + NG * 64;                 // NG*32

    unsigned bE = (NE + 255) / 256;
    unsigned bN = (NN + 255) / 256;
    unsigned bN32 = (NN * 32 + 255) / 256;
    unsigned bN64 = (NN * 64 + 255) / 256;
    unsigned bG8 = (NN + 7) / 8;

    // ---- CSR build (+ dis) ----
    k_zeroi<<<bN, 256, 0, stream>>>(cursor, NN);
    k_count<<<bE, 256, 0, stream>>>(dst, cursor);
    k_dis<<<bN, 256, 0, stream>>>(cursor, dis);
    k_scan<<<1, 1024, 0, stream>>>(cursor, rowptr);
    k_zeroi<<<bN, 256, 0, stream>>>(cursor, NN);
    const int SCAT_BLOCKS = 2048;  // 256 blocks per dst-range group
    k_scatter_r<<<SCAT_BLOCKS, 256, 0, stream>>>(src, dst, rowptr, cursor, srcs, SCAT_BLOCKS);

    // zero pooled buffers early (layer-3 gather pools into them)
    long zlen = (long)NG * (HD + XD) + NG;
    k_zero<<<(unsigned)((zlen + 255) / 256), 256, 0, stream>>>(z, zlen);

    // ---- layer 1 ----
    k_padx16<<<(NN * 8 + 255) / 256, 256, 0, stream>>>(x, dis, xpd);
    k_gather_x8<<<(NN + 31) / 32, 256, 0, stream>>>(xpd, rowptr, srcs, dis, aggx);
    k_xform9<<<bN64, 256, 0, stream>>>(aggx, W1, b1, A);  // A = h1

    // ---- layer 2 ----
    k_xform64d<<<bN32, 256, 0, stream>>>(A, W2, dis, B16);
    k_gather64b<0><<<bG8, 256, 0, stream>>>(B16, rowptr, srcs, dis, b2, batch, z, A);  // A = h2

    // ---- layer 3 (pool fused) ----
    k_xform64d<<<bN32, 256, 0, stream>>>(A, W3, dis, B16);
    k_gather64b<1><<<bG8, 256, 0, stream>>>(B16, rowptr, srcs, dis, b3, batch, z, A);

    // ---- pooling finalize ----
    k_cnt<<<bN, 256, 0, stream>>>(batch, cnt);
    k_zfin<<<(NG * (HD + XD) + 255) / 256, 256, 0, stream>>>(z, cnt, extra);

    // ---- MLP head ----
    k_mm<96, 128><<<(NG * 128 + 255) / 256, 256, 0, stream>>>(z, Wm0, bm0, t0);
    k_bn_relu<128><<<128, 256, 0, stream>>>(t0, g0, be0);
    k_mm<128, 64><<<(NG * 64 + 255) / 256, 256, 0, stream>>>(t0, Wm1, bm1, t1);
    k_bn_relu<64><<<64, 256, 0, stream>>>(t1, g1, be1);
    k_mm<64, 32><<<(NG * 32 + 255) / 256, 256, 0, stream>>>(t1, Wm2, bm2, t2);
    k_bn_relu<32><<<32, 256, 0, stream>>>(t2, g2, be2);
    k_final<<<(NG + 255) / 256, 256, 0, stream>>>(t2, Wm3, bm3, (float*)d_out);
}